// Round 7
// baseline (360.830 us; speedup 1.0000x reference)
//
#include <hip/hip_runtime.h>

#define NN 100000
#define DD 128

typedef __attribute__((ext_vector_type(8))) short bf16x8;
typedef __attribute__((ext_vector_type(4))) float f32x4;
typedef __attribute__((ext_vector_type(2))) float f32x2;

__device__ __forceinline__ float bf2f(unsigned short u) {
    union { unsigned int i; float f; } v;
    v.i = ((unsigned int)u) << 16;
    return v.f;
}

__device__ __forceinline__ unsigned short f2bf(float f) {
    union { float f; unsigned int i; } v;
    v.f = f;
    unsigned int x = v.i;
    return (unsigned short)((x + 0x7FFFu + ((x >> 16) & 1u)) >> 16);
}

__device__ __forceinline__ float2 load2(const float* p, int i2) {
    return ((const float2*)p)[i2];
}

// unpack one u32 (2 packed bf16) into {lo, hi} f32 pair: shl + and only.
__device__ __forceinline__ f32x2 cvt2(unsigned int u) {
    union { unsigned int i; float f; } lo, hi;
    lo.i = u << 16;
    hi.i = u & 0xffff0000u;
    return (f32x2){lo.f, hi.f};
}

// 8 bf16 elements from bf16 or fp32 storage (for GEMM A loads)
__device__ __forceinline__ bf16x8 load8_bf(const unsigned short* p) {
    return *((const bf16x8*)p);
}
__device__ __forceinline__ bf16x8 load8_bf(const float* p) {
    float4 a = ((const float4*)p)[0];
    float4 b = ((const float4*)p)[1];
    bf16x8 r;
    r[0] = (short)f2bf(a.x); r[1] = (short)f2bf(a.y);
    r[2] = (short)f2bf(a.z); r[3] = (short)f2bf(a.w);
    r[4] = (short)f2bf(b.x); r[5] = (short)f2bf(b.y);
    r[6] = (short)f2bf(b.z); r[7] = (short)f2bf(b.w);
    return r;
}

// ---- Round-8: atomic-free CSR build (kept; it was the r7->r8 win) ----
//   1. hist_buckets: LDS histogram of dst>>8 -> bucket counts.
//   2. scan_buckets: 1-block scan -> bucket offsets.
//   3. partition_edges: single edge read; LDS rank; coalesced pair writes.
//   4. build_csr: one workgroup per bucket; LDS counting sort; coalesced
//      csr + off output. Zero per-edge global atomics anywhere.

#define PCH 16       // edges per thread in hist/partition (4096 per block)
#define NBUKMAX 512  // max buckets (N <= 131072)
#define CAP 12288    // LDS staging capacity (pairs) per bucket; mean ~4096

__global__ __launch_bounds__(256) void hist_buckets(
    const int* __restrict__ ei, int E, int* __restrict__ bcnt, int nbuk) {
    __shared__ int is64_s;
    __shared__ int hl[NBUKMAX];
    int tid = threadIdx.x;
    for (int i = tid; i < nbuk; i += 256) hl[i] = 0;
    if (tid < 64) {
        int ok = (ei[2 * tid + 1] == 0);
        int all = __all(ok);
        if (tid == 0) is64_s = all;
    }
    __syncthreads();
    int is64 = is64_s;
    int e0 = blockIdx.x * (256 * PCH) + tid;
#pragma unroll
    for (int c = 0; c < PCH; c++) {
        int e = e0 + c * 256;
        if (e < E) {
            int d = is64 ? ei[2 * (E + e)] : ei[E + e];
            atomicAdd(&hl[d >> 8], 1);
        }
    }
    __syncthreads();
    for (int i = tid; i < nbuk; i += 256) {
        int v = hl[i];
        if (v) atomicAdd(&bcnt[i], v);
    }
}

// 1 block, 512 threads: exclusive scan of nbuk (<=512) bucket counts.
// Also writes boff[nbuk] = E (total) and off[N] = E.
__global__ void scan_buckets(const int* __restrict__ bcnt, int nbuk,
                             int* __restrict__ boff, int* __restrict__ offN, int E) {
    __shared__ int wsum[8];
    int tid = threadIdx.x;
    int lane = tid & 63, wid = tid >> 6;
    int v = (tid < nbuk) ? bcnt[tid] : 0;
    int s = v;
#pragma unroll
    for (int dl = 1; dl < 64; dl <<= 1) {
        int t = __shfl_up(s, dl, 64);
        if (lane >= dl) s += t;
    }
    if (lane == 63) wsum[wid] = s;
    __syncthreads();
    int w = 0;
#pragma unroll
    for (int i = 0; i < 8; i++) w += (i < wid) ? wsum[i] : 0;
    if (tid < nbuk) boff[tid] = w + s - v;      // exclusive
    if (tid == nbuk - 1) boff[nbuk] = w + s;    // total (== E)
    if (tid == 0) offN[0] = E;                  // off[N]
}

__global__ __launch_bounds__(256) void partition_edges(
    const int* __restrict__ ei, int E, const int* __restrict__ boff,
    int* __restrict__ bcur, unsigned long long* __restrict__ pairs, int nbuk) {
    __shared__ int is64_s;
    __shared__ int cntb[NBUKMAX];
    __shared__ int baseb[NBUKMAX];
    __shared__ int boffb[NBUKMAX];
    int tid = threadIdx.x;
    for (int i = tid; i < nbuk; i += 256) {
        cntb[i] = 0;
        boffb[i] = boff[i];
    }
    if (tid < 64) {
        int ok = (ei[2 * tid + 1] == 0);
        int all = __all(ok);
        if (tid == 0) is64_s = all;
    }
    __syncthreads();
    int is64 = is64_s;
    int e0 = blockIdx.x * (256 * PCH) + tid;

    int dv[PCH], sv[PCH], bl[PCH];
    bool va[PCH];
    // Issue all loads first (independent) so HBM latency is paid once.
#pragma unroll
    for (int c = 0; c < PCH; c++) {
        int e = e0 + c * 256;
        va[c] = (e < E);
        dv[c] = va[c] ? (is64 ? ei[2 * (E + e)] : ei[E + e]) : 0;
        sv[c] = va[c] ? (is64 ? ei[2 * e] : ei[e]) : 0;
        bl[c] = 0;
    }
    // Rank within block per bucket (LDS atomics only).
#pragma unroll
    for (int c = 0; c < PCH; c++) {
        if (va[c]) {
            int b = dv[c] >> 8;
            int l = atomicAdd(&cntb[b], 1);
            bl[c] = (b << 16) | l;  // l < 4096
        }
    }
    __syncthreads();
    // One global reservation per (block, bucket).
    for (int i = tid; i < nbuk; i += 256) {
        int cb = cntb[i];
        baseb[i] = cb ? atomicAdd(&bcur[i], cb) : 0;
    }
    __syncthreads();
    // Coalesced pair writes: contiguous run (~10 pairs avg) per (block,bucket).
#pragma unroll
    for (int c = 0; c < PCH; c++) {
        if (va[c]) {
            int b = bl[c] >> 16, l = bl[c] & 0xffff;
            pairs[(size_t)(boffb[b] + baseb[b] + l)] =
                ((unsigned long long)(unsigned int)dv[c] << 32) | (unsigned int)sv[c];
        }
    }
}

// One workgroup per 256-node bucket: LDS counting sort, zero global atomics.
// Emits both csr (coalesced) and off (coalesced).
__global__ __launch_bounds__(256) void build_csr(
    const unsigned long long* __restrict__ pairs, const int* __restrict__ boff,
    int* __restrict__ off, int* __restrict__ csr, int* __restrict__ cur, int N) {
    int b = blockIdx.x;
    int lo = b << 8;
    if (lo >= N) return;
    int hi = min(lo + 256, N);
    int nn = hi - lo;
    int base = boff[b];
    int pcount = boff[b + 1] - base;

    __shared__ int cnt_l[256];
    __shared__ int start_l[256];
    __shared__ int cur_l[256];
    __shared__ int wsum[4];
    __shared__ int lds_csr[CAP];

    int tid = threadIdx.x;
    cnt_l[tid] = 0;
    __syncthreads();

    // local per-node histogram (LDS atomics)
    for (int i = tid; i < pcount; i += 256) {
        int d = (int)(pairs[base + i] >> 32);
        atomicAdd(&cnt_l[d - lo], 1);
    }
    __syncthreads();

    // exclusive scan over 256 local counts (wave scan + cross-wave)
    int v = cnt_l[tid];
    int s = v;
    int lane = tid & 63, wid = tid >> 6;
#pragma unroll
    for (int dl = 1; dl < 64; dl <<= 1) {
        int t = __shfl_up(s, dl, 64);
        if (lane >= dl) s += t;
    }
    if (lane == 63) wsum[wid] = s;
    __syncthreads();
    int w = 0;
#pragma unroll
    for (int i = 0; i < 4; i++) w += (i < wid) ? wsum[i] : 0;
    int excl = w + s - v;
    start_l[tid] = excl;
    cur_l[tid] = excl;
    if (tid < nn) off[lo + tid] = base + excl;  // coalesced off write
    __syncthreads();

    if (pcount <= CAP) {
        // scatter into LDS staging at final positions
        for (int i = tid; i < pcount; i += 256) {
            unsigned long long p = pairs[base + i];
            int d = (int)(p >> 32) - lo;
            int pos = atomicAdd(&cur_l[d], 1);
            lds_csr[pos] = (int)(p & 0xffffffffu);
        }
        __syncthreads();
        // fully coalesced csr write
        for (int i = tid; i < pcount; i += 256) csr[base + i] = lds_csr[i];
    } else {
        // degenerate-distribution fallback (never hit on uniform data):
        // bucket exclusively owned by this block; global cur[] pre-zeroed.
        for (int i = tid; i < pcount; i += 256) {
            unsigned long long p = pairs[base + i];
            int dg = (int)(p >> 32);
            int q = atomicAdd(&cur[dg], 1);
            csr[base + start_l[dg - lo] + q] = (int)(p & 0xffffffffu);
        }
    }
}

__global__ void cast_bf16(const float* __restrict__ in, unsigned short* __restrict__ out,
                          int n4) {
    int i = blockIdx.x * blockDim.x + threadIdx.x;
    if (i >= n4) return;
    float4 v = ((const float4*)in)[i];
    ushort4 o;
    o.x = f2bf(v.x); o.y = f2bf(v.y); o.z = f2bf(v.z); o.w = f2bf(v.w);
    ((ushort4*)out)[i] = o;
}

// All 4 weight transposes in one launch. Wt[f][koff+k] = bf16(W[k][f]).
// grid 64: blockIdx>>4 selects matrix, &15 selects 32x32 sub-tile.
__global__ void prep_weights(const float* __restrict__ Wl1, const float* __restrict__ Wr1,
                             const float* __restrict__ Wl2, const float* __restrict__ Wr2,
                             unsigned short* __restrict__ Wt1, unsigned short* __restrict__ Wt2) {
    __shared__ float t[32][33];
    int which = blockIdx.x >> 4;
    const float* W = (which == 0) ? Wl1 : (which == 1) ? Wr1 : (which == 2) ? Wl2 : Wr2;
    unsigned short* Wt = (which < 2) ? Wt1 : Wt2;
    int koff = (which & 1) * 128;
    int b = blockIdx.x & 15;
    int bx = b & 3, by = b >> 2;
    int c = threadIdx.x & 31, r8 = threadIdx.x >> 5;
#pragma unroll
    for (int i = 0; i < 4; i++) {
        int r = r8 + i * 8;
        t[r][c] = W[(by * 32 + r) * 128 + bx * 32 + c];
    }
    __syncthreads();
#pragma unroll
    for (int i = 0; i < 4; i++) {
        int r = r8 + i * 8;
        Wt[(bx * 32 + r) * 256 + koff + by * 32 + c] = f2bf(t[c][r]);
    }
}

// ---- Round-11: 4-nodes-per-wave pipelined aggregate ----
// Round-10 counters: 56.8 us, FETCH 177.7 MB, hbm 45.7%, VALU 66%, occ 62%,
// conflicts 0 -> nothing saturated. Cause: ONE node per wave; avg degree 16
// means each wave's life is one serial chain (off -> csr ~600cyc -> shfl ->
// gather ~700cyc -> ACC -> reduce -> store ~= 2us) doing only 16 edges.
// Fix: 4 nodes/wave: (a) one coalesced off load (shfl-broadcast); (b) all 4
// csr-chunk loads issued up-front; (c) node g+1's gathers issued BEFORE node
// g's final ACC/reduce/store -> a gather always in flight per wave. Degree>64
// handled by rare per-node chunk fallback; per-node f32 sum order unchanged.
#define ACC8(u) do { \
    acc[0] += cvt2((u).x); acc[1] += cvt2((u).y); \
    acc[2] += cvt2((u).z); acc[3] += cvt2((u).w); } while (0)

#define GATH4(D0, D1, D2, D3, crg, cdeg, b) do { \
    int i0 = (b) * 16 + e, i1 = i0 + 4, i2 = i0 + 8, i3 = i0 + 12; \
    int t0 = __shfl((crg), i0, 64), t1 = __shfl((crg), i1, 64), \
        t2 = __shfl((crg), i2, 64), t3 = __shfl((crg), i3, 64); \
    D0 = make_uint4(0, 0, 0, 0); D1 = D0; D2 = D0; D3 = D0; \
    if (i0 < (cdeg)) D0 = *((const uint4*)(feat + (size_t)t0 * 128 + q * 8)); \
    if (i1 < (cdeg)) D1 = *((const uint4*)(feat + (size_t)t1 * 128 + q * 8)); \
    if (i2 < (cdeg)) D2 = *((const uint4*)(feat + (size_t)t2 * 128 + q * 8)); \
    if (i3 < (cdeg)) D3 = *((const uint4*)(feat + (size_t)t3 * 128 + q * 8)); \
} while (0)

__global__ __launch_bounds__(256) void aggregate_bf(
    const unsigned short* __restrict__ feat,
    const int* __restrict__ off, const int* __restrict__ csr,
    unsigned short* __restrict__ mean, int N, const int* __restrict__ limp) {
    int lim = limp ? min(N, limp[0]) : N;
    int nb0 = (blockIdx.x * 4 + (int)(threadIdx.x >> 6)) * 4;
    if (nb0 >= lim) return;
    int lane = threadIdx.x & 63;
    int e = lane >> 4, q = lane & 15;

    // off[nb0..nb0+4] in one coalesced load; broadcast via shfl.
    int offv = off[min(nb0 + min(lane, 4), N)];
    int s0g[4], dg[4], cr[4];
#pragma unroll
    for (int g = 0; g < 4; g++) {
        int s0 = __shfl(offv, g, 64);
        int s1 = __shfl(offv, g + 1, 64);
        bool valid = (nb0 + g) < lim;
        s0g[g] = s0;
        dg[g] = valid ? (s1 - s0) : 0;
        int nd = min(dg[g], 64);
        cr[g] = (lane < nd) ? csr[s0 + lane] : 0;   // 4 independent loads
    }

    f32x2 acc[4];
    uint4 C0, C1, C2, C3, P0, P1, P2, P3;
    {
        int cd0 = min(dg[0], 64);
        GATH4(C0, C1, C2, C3, cr[0], cd0, 0);
    }

#pragma unroll
    for (int g = 0; g < 4; g++) {
        int cdeg = min(dg[g], 64);
        int nbt = (cdeg + 15) >> 4;
#pragma unroll
        for (int t = 0; t < 4; t++) acc[t] = (f32x2){0.f, 0.f};
        for (int b = 1; b < nbt; b++) {
            GATH4(P0, P1, P2, P3, cr[g], cdeg, b);
            ACC8(C0); ACC8(C1); ACC8(C2); ACC8(C3);
            C0 = P0; C1 = P1; C2 = P2; C3 = P3;
        }
        // issue next node's first gather batch before this node's tail work
        if (g < 3) {
            int cdn = min(dg[g + 1], 64);
            GATH4(P0, P1, P2, P3, cr[g + 1], cdn, 0);
        }
        ACC8(C0); ACC8(C1); ACC8(C2); ACC8(C3);

        // rare: degree > 64 remainder (chunked, reloads csr)
        int s1e = s0g[g] + dg[g];
        for (int c0 = s0g[g] + 64; c0 < s1e; c0 += 64) {
            int cd2 = min(64, s1e - c0);
            int cr2 = (lane < cd2) ? csr[c0 + lane] : 0;
            int nb2 = (cd2 + 15) >> 4;
            for (int b = 0; b < nb2; b++) {
                uint4 E0, E1, E2, E3;
                GATH4(E0, E1, E2, E3, cr2, cd2, b);
                ACC8(E0); ACC8(E1); ACC8(E2); ACC8(E3);
            }
        }

        // cross-slot reduce: one 64-bit shuffle per f32x2 per step
#pragma unroll
        for (int t = 0; t < 4; t++) {
            union { f32x2 v; double d; } a, bb;
            a.v = acc[t];
            bb.d = __shfl_xor(a.d, 16, 64); a.v += bb.v;
            bb.d = __shfl_xor(a.d, 32, 64); a.v += bb.v;
            acc[t] = a.v;
        }
        float inv = (dg[g] > 0) ? (1.0f / (float)dg[g]) : 0.0f;
        if (e == 0 && (nb0 + g) < lim) {
            bf16x8 o;
#pragma unroll
            for (int t = 0; t < 4; t++) {
                o[2 * t]     = (short)f2bf(acc[t].x * inv);
                o[2 * t + 1] = (short)f2bf(acc[t].y * inv);
            }
            *((bf16x8*)(mean + (size_t)(nb0 + g) * 128 + q * 8)) = o;
        }
        if (g < 3) { C0 = P0; C1 = P1; C2 = P2; C3 = P3; }
    }
}

// Fallback scalar aggregate for fp32 features (non-big path only)
__global__ void aggregate_f32(const float* __restrict__ feat,
                              const int* __restrict__ off, const int* __restrict__ csr,
                              unsigned short* __restrict__ mean, int N) {
    int node = blockIdx.x * (blockDim.x >> 6) + (threadIdx.x >> 6);
    if (node >= N) return;
    int lane = threadIdx.x & 63;
    int s0 = off[node], s1 = off[node + 1];
    float ax = 0.f, ay = 0.f;
    for (int j = s0; j < s1; j++) {
        int s = csr[j];
        float2 v = load2(feat, s * 64 + lane);
        ax += v.x; ay += v.y;
    }
    float inv = (s1 > s0) ? (1.0f / (float)(s1 - s0)) : 0.0f;
    unsigned int p = (unsigned int)f2bf(ax * inv) | ((unsigned int)f2bf(ay * inv) << 16);
    ((unsigned int*)mean)[node * 64 + lane] = p;
}

// ---- Round-10: barrier-free direct-load GEMM (kept; r9->r10 win) ----
// out[n][f] = sum_k A1[n][k]*Wt[f][k] (k<128) + A2[n][k]*Wt[f][128+k] + bias[f]
template <typename TA2, typename TO>
__global__ __launch_bounds__(256) void gemm_mfma(
    const unsigned short* __restrict__ A1, const TA2* __restrict__ A2,
    const unsigned short* __restrict__ Wt, const float* __restrict__ bias,
    TO* __restrict__ out, int Arows, int Nlimit, const int* __restrict__ origp) {
    int lim = Nlimit;
    if (origp) lim = min(lim, origp[0]);
    int n0 = blockIdx.x * 64;
    if (n0 >= lim) return;

    int tid = threadIdx.x;
    int lane = tid & 63;
    int wid = tid >> 6;
    int wm = wid >> 1, wn = wid & 1;
    int qd = lane >> 4, l16 = lane & 15;

    // A rows this wave reads (clamped for the tail block; clamped rows'
    // outputs are never stored since n < lim <= Arows).
    int r0 = min(n0 + wm * 32 + l16, Arows - 1);
    int r1 = min(n0 + wm * 32 + 16 + l16, Arows - 1);

    f32x4 acc[2][4];
#pragma unroll
    for (int a = 0; a < 2; a++)
#pragma unroll
        for (int b = 0; b < 4; b++) acc[a][b] = (f32x4){0.f, 0.f, 0.f, 0.f};

#pragma unroll
    for (int ks = 0; ks < 8; ks++) {
        int kb = (ks & 3) * 32;          // k offset within the 128-wide A row
        bf16x8 a0, a1;
        if (ks < 4) {                    // phase 0: A1 (mean) x Wl
            a0 = load8_bf(A1 + (size_t)r0 * 128 + kb + qd * 8);
            a1 = load8_bf(A1 + (size_t)r1 * 128 + kb + qd * 8);
        } else {                         // phase 1: A2 (root) x Wr
            a0 = load8_bf(A2 + (size_t)r0 * 128 + kb + qd * 8);
            a1 = load8_bf(A2 + (size_t)r1 * 128 + kb + qd * 8);
        }
#pragma unroll
        for (int tn = 0; tn < 4; tn++) {
            int f = wn * 64 + tn * 16 + l16;
            bf16x8 bfrag = *((const bf16x8*)(Wt + f * 256 + ks * 32 + qd * 8));
            acc[0][tn] = __builtin_amdgcn_mfma_f32_16x16x32_bf16(a0, bfrag, acc[0][tn], 0, 0, 0);
            acc[1][tn] = __builtin_amdgcn_mfma_f32_16x16x32_bf16(a1, bfrag, acc[1][tn], 0, 0, 0);
        }
    }

#pragma unroll
    for (int tn = 0; tn < 4; tn++) {
        int f = wn * 64 + tn * 16 + l16;
        float bv = bias[f];
#pragma unroll
        for (int tm = 0; tm < 2; tm++) {
#pragma unroll
            for (int r = 0; r < 4; r++) {
                int n = n0 + wm * 32 + tm * 16 + qd * 4 + r;
                if (n < lim) {
                    float val = acc[tm][tn][r] + bv;
                    if constexpr (__is_same(TO, float))
                        out[n * 128 + f] = val;
                    else
                        out[n * 128 + f] = f2bf(val);
                }
            }
        }
    }
}

extern "C" void kernel_launch(void* const* d_in, const int* in_sizes, int n_in,
                              void* d_out, int out_size, void* d_ws, size_t ws_size,
                              hipStream_t stream) {
    const float* x   = (const float*)d_in[0];
    const int*   ei  = (const int*)d_in[1];
    const int*   org = (const int*)d_in[2];
    const float* Wl1 = (const float*)d_in[3];
    const float* bl1 = (const float*)d_in[4];
    const float* Wr1 = (const float*)d_in[5];
    const float* Wl2 = (const float*)d_in[6];
    const float* bl2 = (const float*)d_in[7];
    const float* Wr2 = (const float*)d_in[8];
    float* out = (float*)d_out;

    const int N = in_sizes[0] / DD;
    const int E = in_sizes[1] / 2;

    size_t szFeat = (size_t)N * DD * 2;          // bf16 feature matrix
    size_t szBase = 2 * szFeat                    // mean + h
                  + 2 * 65536                     // Wt1 + Wt2
                  + (size_t)N * 4 + 4096          // cur + bcnt + bcur
                  + (size_t)(N + 1) * 4           // off
                  + 4096                          // boff
                  + (size_t)E * 4;                // csr
    bool big = ws_size >= szBase + szFeat + 4096; // room for bf16 x too?

    char* ws = (char*)d_ws;
    unsigned short* mean = (unsigned short*)ws;  ws += szFeat;
    unsigned short* h    = (unsigned short*)ws;  ws += szFeat;
    unsigned short* xb   = nullptr;
    if (big) { xb = (unsigned short*)ws; ws += szFeat; }
    unsigned short* Wt1 = (unsigned short*)ws;  ws += 65536;
    unsigned short* Wt2 = (unsigned short*)ws;  ws += 65536;
    int* cur  = (int*)ws;  ws += (size_t)N * 4;   // fallback only
    int* bcnt = (int*)ws;  ws += 2048;            // cur+bcnt+bcur: one memset
    int* bcur = (int*)ws;  ws += 2048;
    int* off  = (int*)ws;  ws += (size_t)(N + 1) * 4;
    int* boff = (int*)ws;  ws += 4096;
    int* csr  = (int*)ws;

    // pairs buffer (E x 8 B) aliases mean+h (2*szFeat >= E*8 for this shape);
    // mean/h are first written by aggregate/gemm, strictly after build_csr
    // in stream order, so the aliasing is dead by then.
    unsigned long long* pairs = (unsigned long long*)mean;

    int nbuk = (N + 255) >> 8;                  // 391 for N=100000 (<= NBUKMAX)
    int edgeGrid = (E + 256 * PCH - 1) / (256 * PCH);

    // --- CSR build (no per-edge global atomics anywhere) ---
    hipMemsetAsync(cur, 0, (size_t)N * 4 + 4096, stream);   // cur + bcnt + bcur
    hist_buckets<<<edgeGrid, 256, 0, stream>>>(ei, E, bcnt, nbuk);
    scan_buckets<<<1, 512, 0, stream>>>(bcnt, nbuk, boff, off + N, E);
    partition_edges<<<edgeGrid, 256, 0, stream>>>(ei, E, boff, bcur, pairs, nbuk);
    build_csr<<<nbuk, 256, 0, stream>>>(pairs, boff, off, csr, cur, N);

    // --- weight prep (Wt[f][k]: k<128 = Wl, k>=128 = Wr) ---
    prep_weights<<<64, 256, 0, stream>>>(Wl1, Wr1, Wl2, Wr2, Wt1, Wt2);

    int aggGrid  = (N + 15) / 16;   // 4 waves x 4 nodes per block
    int aggGridF = (N + 3) / 4;     // f32 fallback: 4 nodes per block
    int gemmGrid = (N + 63) / 64;

    if (big) {
        cast_bf16<<<(N * DD / 4 + 255) / 256, 256, 0, stream>>>(x, xb, N * DD / 4);
        aggregate_bf<<<aggGrid, 256, 0, stream>>>(xb, off, csr, mean, N, nullptr);
        gemm_mfma<unsigned short, unsigned short><<<gemmGrid, 256, 0, stream>>>(
            mean, xb, Wt1, bl1, h, N, N, nullptr);
    } else {
        aggregate_f32<<<aggGridF, 256, 0, stream>>>(x, off, csr, mean, N);
        gemm_mfma<float, unsigned short><<<gemmGrid, 256, 0, stream>>>(
            mean, x, Wt1, bl1, h, N, N, nullptr);
    }
    aggregate_bf<<<aggGrid, 256, 0, stream>>>(h, off, csr, mean, N, org);
    gemm_mfma<unsigned short, float><<<gemmGrid, 256, 0, stream>>>(
        mean, h, Wt2, bl2, out, N, N, org);
}

// Round 8
// 330.889 us; speedup vs baseline: 1.0905x; 1.0905x over previous
//
#include <hip/hip_runtime.h>

#define NN 100000
#define DD 128

typedef __attribute__((ext_vector_type(8))) short bf16x8;
typedef __attribute__((ext_vector_type(4))) float f32x4;
typedef __attribute__((ext_vector_type(2))) float f32x2;

__device__ __forceinline__ float bf2f(unsigned short u) {
    union { unsigned int i; float f; } v;
    v.i = ((unsigned int)u) << 16;
    return v.f;
}

__device__ __forceinline__ unsigned short f2bf(float f) {
    union { float f; unsigned int i; } v;
    v.f = f;
    unsigned int x = v.i;
    return (unsigned short)((x + 0x7FFFu + ((x >> 16) & 1u)) >> 16);
}

__device__ __forceinline__ float2 load2(const float* p, int i2) {
    return ((const float2*)p)[i2];
}

// unpack one u32 (2 packed bf16) into {lo, hi} f32 pair: shl + and only.
__device__ __forceinline__ f32x2 cvt2(unsigned int u) {
    union { unsigned int i; float f; } lo, hi;
    lo.i = u << 16;
    hi.i = u & 0xffff0000u;
    return (f32x2){lo.f, hi.f};
}

// 8 bf16 elements from bf16 or fp32 storage (for GEMM A loads)
__device__ __forceinline__ bf16x8 load8_bf(const unsigned short* p) {
    return *((const bf16x8*)p);
}
__device__ __forceinline__ bf16x8 load8_bf(const float* p) {
    float4 a = ((const float4*)p)[0];
    float4 b = ((const float4*)p)[1];
    bf16x8 r;
    r[0] = (short)f2bf(a.x); r[1] = (short)f2bf(a.y);
    r[2] = (short)f2bf(a.z); r[3] = (short)f2bf(a.w);
    r[4] = (short)f2bf(b.x); r[5] = (short)f2bf(b.y);
    r[6] = (short)f2bf(b.z); r[7] = (short)f2bf(b.w);
    return r;
}

// ---- Round-8: atomic-free CSR build (kept; it was the r7->r8 win) ----

#define PCH 16       // edges per thread in hist/partition (4096 per block)
#define NBUKMAX 512  // max buckets (N <= 131072)
#define CAP 12288    // LDS staging capacity (pairs) per bucket; mean ~4096

__global__ __launch_bounds__(256) void hist_buckets(
    const int* __restrict__ ei, int E, int* __restrict__ bcnt, int nbuk) {
    __shared__ int is64_s;
    __shared__ int hl[NBUKMAX];
    int tid = threadIdx.x;
    for (int i = tid; i < nbuk; i += 256) hl[i] = 0;
    if (tid < 64) {
        int ok = (ei[2 * tid + 1] == 0);
        int all = __all(ok);
        if (tid == 0) is64_s = all;
    }
    __syncthreads();
    int is64 = is64_s;
    int e0 = blockIdx.x * (256 * PCH) + tid;
#pragma unroll
    for (int c = 0; c < PCH; c++) {
        int e = e0 + c * 256;
        if (e < E) {
            int d = is64 ? ei[2 * (E + e)] : ei[E + e];
            atomicAdd(&hl[d >> 8], 1);
        }
    }
    __syncthreads();
    for (int i = tid; i < nbuk; i += 256) {
        int v = hl[i];
        if (v) atomicAdd(&bcnt[i], v);
    }
}

// 1 block, 512 threads: exclusive scan of nbuk (<=512) bucket counts.
// Also writes boff[nbuk] = E (total) and off[N] = E.
__global__ void scan_buckets(const int* __restrict__ bcnt, int nbuk,
                             int* __restrict__ boff, int* __restrict__ offN, int E) {
    __shared__ int wsum[8];
    int tid = threadIdx.x;
    int lane = tid & 63, wid = tid >> 6;
    int v = (tid < nbuk) ? bcnt[tid] : 0;
    int s = v;
#pragma unroll
    for (int dl = 1; dl < 64; dl <<= 1) {
        int t = __shfl_up(s, dl, 64);
        if (lane >= dl) s += t;
    }
    if (lane == 63) wsum[wid] = s;
    __syncthreads();
    int w = 0;
#pragma unroll
    for (int i = 0; i < 8; i++) w += (i < wid) ? wsum[i] : 0;
    if (tid < nbuk) boff[tid] = w + s - v;      // exclusive
    if (tid == nbuk - 1) boff[nbuk] = w + s;    // total (== E)
    if (tid == 0) offN[0] = E;                  // off[N]
}

__global__ __launch_bounds__(256) void partition_edges(
    const int* __restrict__ ei, int E, const int* __restrict__ boff,
    int* __restrict__ bcur, unsigned long long* __restrict__ pairs, int nbuk) {
    __shared__ int is64_s;
    __shared__ int cntb[NBUKMAX];
    __shared__ int baseb[NBUKMAX];
    __shared__ int boffb[NBUKMAX];
    int tid = threadIdx.x;
    for (int i = tid; i < nbuk; i += 256) {
        cntb[i] = 0;
        boffb[i] = boff[i];
    }
    if (tid < 64) {
        int ok = (ei[2 * tid + 1] == 0);
        int all = __all(ok);
        if (tid == 0) is64_s = all;
    }
    __syncthreads();
    int is64 = is64_s;
    int e0 = blockIdx.x * (256 * PCH) + tid;

    int dv[PCH], sv[PCH], bl[PCH];
    bool va[PCH];
    // Issue all loads first (independent) so HBM latency is paid once.
#pragma unroll
    for (int c = 0; c < PCH; c++) {
        int e = e0 + c * 256;
        va[c] = (e < E);
        dv[c] = va[c] ? (is64 ? ei[2 * (E + e)] : ei[E + e]) : 0;
        sv[c] = va[c] ? (is64 ? ei[2 * e] : ei[e]) : 0;
        bl[c] = 0;
    }
    // Rank within block per bucket (LDS atomics only).
#pragma unroll
    for (int c = 0; c < PCH; c++) {
        if (va[c]) {
            int b = dv[c] >> 8;
            int l = atomicAdd(&cntb[b], 1);
            bl[c] = (b << 16) | l;  // l < 4096
        }
    }
    __syncthreads();
    // One global reservation per (block, bucket).
    for (int i = tid; i < nbuk; i += 256) {
        int cb = cntb[i];
        baseb[i] = cb ? atomicAdd(&bcur[i], cb) : 0;
    }
    __syncthreads();
    // Coalesced pair writes: contiguous run (~10 pairs avg) per (block,bucket).
#pragma unroll
    for (int c = 0; c < PCH; c++) {
        if (va[c]) {
            int b = bl[c] >> 16, l = bl[c] & 0xffff;
            pairs[(size_t)(boffb[b] + baseb[b] + l)] =
                ((unsigned long long)(unsigned int)dv[c] << 32) | (unsigned int)sv[c];
        }
    }
}

// One workgroup per 256-node bucket: LDS counting sort, zero global atomics.
// Emits both csr (coalesced) and off (coalesced).
__global__ __launch_bounds__(256) void build_csr(
    const unsigned long long* __restrict__ pairs, const int* __restrict__ boff,
    int* __restrict__ off, int* __restrict__ csr, int* __restrict__ cur, int N) {
    int b = blockIdx.x;
    int lo = b << 8;
    if (lo >= N) return;
    int hi = min(lo + 256, N);
    int nn = hi - lo;
    int base = boff[b];
    int pcount = boff[b + 1] - base;

    __shared__ int cnt_l[256];
    __shared__ int start_l[256];
    __shared__ int cur_l[256];
    __shared__ int wsum[4];
    __shared__ int lds_csr[CAP];

    int tid = threadIdx.x;
    cnt_l[tid] = 0;
    __syncthreads();

    // local per-node histogram (LDS atomics)
    for (int i = tid; i < pcount; i += 256) {
        int d = (int)(pairs[base + i] >> 32);
        atomicAdd(&cnt_l[d - lo], 1);
    }
    __syncthreads();

    // exclusive scan over 256 local counts (wave scan + cross-wave)
    int v = cnt_l[tid];
    int s = v;
    int lane = tid & 63, wid = tid >> 6;
#pragma unroll
    for (int dl = 1; dl < 64; dl <<= 1) {
        int t = __shfl_up(s, dl, 64);
        if (lane >= dl) s += t;
    }
    if (lane == 63) wsum[wid] = s;
    __syncthreads();
    int w = 0;
#pragma unroll
    for (int i = 0; i < 4; i++) w += (i < wid) ? wsum[i] : 0;
    int excl = w + s - v;
    start_l[tid] = excl;
    cur_l[tid] = excl;
    if (tid < nn) off[lo + tid] = base + excl;  // coalesced off write
    __syncthreads();

    if (pcount <= CAP) {
        // scatter into LDS staging at final positions
        for (int i = tid; i < pcount; i += 256) {
            unsigned long long p = pairs[base + i];
            int d = (int)(p >> 32) - lo;
            int pos = atomicAdd(&cur_l[d], 1);
            lds_csr[pos] = (int)(p & 0xffffffffu);
        }
        __syncthreads();
        // fully coalesced csr write
        for (int i = tid; i < pcount; i += 256) csr[base + i] = lds_csr[i];
    } else {
        // degenerate-distribution fallback (never hit on uniform data):
        // bucket exclusively owned by this block; global cur[] pre-zeroed.
        for (int i = tid; i < pcount; i += 256) {
            unsigned long long p = pairs[base + i];
            int dg = (int)(p >> 32);
            int q = atomicAdd(&cur[dg], 1);
            csr[base + start_l[dg - lo] + q] = (int)(p & 0xffffffffu);
        }
    }
}

__global__ void cast_bf16(const float* __restrict__ in, unsigned short* __restrict__ out,
                          int n4) {
    int i = blockIdx.x * blockDim.x + threadIdx.x;
    if (i >= n4) return;
    float4 v = ((const float4*)in)[i];
    ushort4 o;
    o.x = f2bf(v.x); o.y = f2bf(v.y); o.z = f2bf(v.z); o.w = f2bf(v.w);
    ((ushort4*)out)[i] = o;
}

// ---- Round-12: fragment-ordered weight layout ----
// r6 totals exposed that the direct-load gemm is still ~55 us: its Wt reads
// have 16 lanes x 16 B at stride 512 B = 64 distinct lines per wave-load at
// 25% line utilization (L2 request-rate bound). Fix: store Wt in the exact
// MFMA fragment order so a wave's bfrag load is ONE contiguous 1 KB run:
//   idx(f,k) = ((f>>4)*8 + (k>>5))*512 + ((k>>3)&3)*128 + (f&15)*8 + (k&7)
// gemm reads Wt + slot*512 + lane*8, slot = (f>>4)*8 + ks.
__global__ void prep_weights(const float* __restrict__ Wl1, const float* __restrict__ Wr1,
                             const float* __restrict__ Wl2, const float* __restrict__ Wr2,
                             unsigned short* __restrict__ Wt1, unsigned short* __restrict__ Wt2) {
    __shared__ float t[32][33];
    int which = blockIdx.x >> 4;
    const float* W = (which == 0) ? Wl1 : (which == 1) ? Wr1 : (which == 2) ? Wl2 : Wr2;
    unsigned short* Wt = (which < 2) ? Wt1 : Wt2;
    int koff = (which & 1) * 128;
    int b = blockIdx.x & 15;
    int bx = b & 3, by = b >> 2;
    int c = threadIdx.x & 31, r8 = threadIdx.x >> 5;
#pragma unroll
    for (int i = 0; i < 4; i++) {
        int r = r8 + i * 8;
        t[r][c] = W[(by * 32 + r) * 128 + bx * 32 + c];
    }
    __syncthreads();
#pragma unroll
    for (int i = 0; i < 4; i++) {
        int r = r8 + i * 8;
        int fi = bx * 32 + r;               // output feature
        int kk = koff + by * 32 + c;        // input k (0..255)
        int idx = ((fi >> 4) * 8 + (kk >> 5)) * 512 + ((kk >> 3) & 3) * 128
                + (fi & 15) * 8 + (kk & 7);
        Wt[idx] = f2bf(t[c][r]);
    }
}

// ---- Round-9 aggregate (reverted r11: 4-nodes/wave cut waves 4x and raised
// VGPR 36->48 -> occupancy 62->45%, dur 56.8->67.4. TLP is the latency hider
// at avg degree 16; one node per wave, 100K waves, is the better point.) ----
#define ACC8(u) do { \
    acc[0] += cvt2((u).x); acc[1] += cvt2((u).y); \
    acc[2] += cvt2((u).z); acc[3] += cvt2((u).w); } while (0)

__global__ __launch_bounds__(256) void aggregate_bf(
    const unsigned short* __restrict__ feat,
    const int* __restrict__ off, const int* __restrict__ csr,
    unsigned short* __restrict__ mean, int N, const int* __restrict__ limp) {
    int lim = limp ? min(N, limp[0]) : N;
    int node = blockIdx.x * 4 + (threadIdx.x >> 6);
    if (node >= lim) return;
    int lane = threadIdx.x & 63;
    int e = lane >> 4, q = lane & 15;
    int s0 = off[node], s1 = off[node + 1];

    f32x2 acc[4];
#pragma unroll
    for (int t = 0; t < 4; t++) acc[t] = (f32x2){0.f, 0.f};

    for (int c0 = s0; c0 < s1; c0 += 64) {
        int cdeg = min(64, s1 - c0);
        int cr = (lane < cdeg) ? csr[c0 + lane] : 0;
        int nb = (cdeg + 15) >> 4;

        uint4 C0 = make_uint4(0, 0, 0, 0), C1 = C0, C2 = C0, C3 = C0;
        {
            int i0 = e, i1 = e + 4, i2 = e + 8, i3 = e + 12;
            int t0 = __shfl(cr, i0, 64), t1 = __shfl(cr, i1, 64),
                t2 = __shfl(cr, i2, 64), t3 = __shfl(cr, i3, 64);
            if (i0 < cdeg) C0 = *((const uint4*)(feat + (size_t)t0 * 128 + q * 8));
            if (i1 < cdeg) C1 = *((const uint4*)(feat + (size_t)t1 * 128 + q * 8));
            if (i2 < cdeg) C2 = *((const uint4*)(feat + (size_t)t2 * 128 + q * 8));
            if (i3 < cdeg) C3 = *((const uint4*)(feat + (size_t)t3 * 128 + q * 8));
        }
        for (int b = 1; b < nb; b++) {
            int i0 = b * 16 + e, i1 = i0 + 4, i2 = i0 + 8, i3 = i0 + 12;
            int t0 = __shfl(cr, i0, 64), t1 = __shfl(cr, i1, 64),
                t2 = __shfl(cr, i2, 64), t3 = __shfl(cr, i3, 64);
            uint4 N0 = make_uint4(0, 0, 0, 0), N1 = N0, N2 = N0, N3 = N0;
            if (i0 < cdeg) N0 = *((const uint4*)(feat + (size_t)t0 * 128 + q * 8));
            if (i1 < cdeg) N1 = *((const uint4*)(feat + (size_t)t1 * 128 + q * 8));
            if (i2 < cdeg) N2 = *((const uint4*)(feat + (size_t)t2 * 128 + q * 8));
            if (i3 < cdeg) N3 = *((const uint4*)(feat + (size_t)t3 * 128 + q * 8));
            ACC8(C0); ACC8(C1); ACC8(C2); ACC8(C3);
            C0 = N0; C1 = N1; C2 = N2; C3 = N3;
        }
        ACC8(C0); ACC8(C1); ACC8(C2); ACC8(C3);
    }

    // cross-slot reduce: one 64-bit shuffle per f32x2 per step
#pragma unroll
    for (int t = 0; t < 4; t++) {
        union { f32x2 v; double d; } a, b;
        a.v = acc[t];
        b.d = __shfl_xor(a.d, 16, 64); a.v += b.v;
        b.d = __shfl_xor(a.d, 32, 64); a.v += b.v;
        acc[t] = a.v;
    }

    int deg = s1 - s0;
    float inv = (deg > 0) ? (1.0f / (float)deg) : 0.0f;
    if (e == 0) {
        bf16x8 o;
#pragma unroll
        for (int t = 0; t < 4; t++) {
            o[2 * t]     = (short)f2bf(acc[t].x * inv);
            o[2 * t + 1] = (short)f2bf(acc[t].y * inv);
        }
        *((bf16x8*)(mean + (size_t)node * 128 + q * 8)) = o;
    }
}

// Fallback scalar aggregate for fp32 features (non-big path only)
__global__ void aggregate_f32(const float* __restrict__ feat,
                              const int* __restrict__ off, const int* __restrict__ csr,
                              unsigned short* __restrict__ mean, int N) {
    int node = blockIdx.x * (blockDim.x >> 6) + (threadIdx.x >> 6);
    if (node >= N) return;
    int lane = threadIdx.x & 63;
    int s0 = off[node], s1 = off[node + 1];
    float ax = 0.f, ay = 0.f;
    for (int j = s0; j < s1; j++) {
        int s = csr[j];
        float2 v = load2(feat, s * 64 + lane);
        ax += v.x; ay += v.y;
    }
    float inv = (s1 > s0) ? (1.0f / (float)(s1 - s0)) : 0.0f;
    unsigned int p = (unsigned int)f2bf(ax * inv) | ((unsigned int)f2bf(ay * inv) << 16);
    ((unsigned int*)mean)[node * 64 + lane] = p;
}

// ---- Round-12: barrier-free GEMM with fragment-ordered Wt ----
// bfrag load = Wt + slot*512 + lane*8: 64 lanes read one contiguous 1 KB run
// (16 fully-used lines vs 64 quarter-used before). A loads use full 64-B
// granules (4 lanes per line). No LDS, no barriers.
// out[n][f] = sum_k A1[n][k]*Wt[f][k] (k<128) + A2[n][k]*Wt[f][128+k] + bias[f]
template <typename TA2, typename TO>
__global__ __launch_bounds__(256) void gemm_mfma(
    const unsigned short* __restrict__ A1, const TA2* __restrict__ A2,
    const unsigned short* __restrict__ Wt, const float* __restrict__ bias,
    TO* __restrict__ out, int Arows, int Nlimit, const int* __restrict__ origp) {
    int lim = Nlimit;
    if (origp) lim = min(lim, origp[0]);
    int n0 = blockIdx.x * 64;
    if (n0 >= lim) return;

    int tid = threadIdx.x;
    int lane = tid & 63;
    int wid = tid >> 6;
    int wm = wid >> 1, wn = wid & 1;
    int qd = lane >> 4, l16 = lane & 15;

    // A rows this wave reads (clamped for the tail block; clamped rows'
    // outputs are never stored since n < lim <= Arows).
    int r0 = min(n0 + wm * 32 + l16, Arows - 1);
    int r1 = min(n0 + wm * 32 + 16 + l16, Arows - 1);

    f32x4 acc[2][4];
#pragma unroll
    for (int a = 0; a < 2; a++)
#pragma unroll
        for (int b = 0; b < 4; b++) acc[a][b] = (f32x4){0.f, 0.f, 0.f, 0.f};

#pragma unroll
    for (int ks = 0; ks < 8; ks++) {
        int kb = (ks & 3) * 32;          // k offset within the 128-wide A row
        bf16x8 a0, a1;
        if (ks < 4) {                    // phase 0: A1 (mean) x Wl
            a0 = load8_bf(A1 + (size_t)r0 * 128 + kb + qd * 8);
            a1 = load8_bf(A1 + (size_t)r1 * 128 + kb + qd * 8);
        } else {                         // phase 1: A2 (root) x Wr
            a0 = load8_bf(A2 + (size_t)r0 * 128 + kb + qd * 8);
            a1 = load8_bf(A2 + (size_t)r1 * 128 + kb + qd * 8);
        }
#pragma unroll
        for (int tn = 0; tn < 4; tn++) {
            int slot = (wn * 4 + tn) * 8 + ks;
            bf16x8 bfrag = *((const bf16x8*)(Wt + slot * 512 + lane * 8));
            acc[0][tn] = __builtin_amdgcn_mfma_f32_16x16x32_bf16(a0, bfrag, acc[0][tn], 0, 0, 0);
            acc[1][tn] = __builtin_amdgcn_mfma_f32_16x16x32_bf16(a1, bfrag, acc[1][tn], 0, 0, 0);
        }
    }

#pragma unroll
    for (int tn = 0; tn < 4; tn++) {
        int f = wn * 64 + tn * 16 + l16;
        float bv = bias[f];
#pragma unroll
        for (int tm = 0; tm < 2; tm++) {
#pragma unroll
            for (int r = 0; r < 4; r++) {
                int n = n0 + wm * 32 + tm * 16 + qd * 4 + r;
                if (n < lim) {
                    float val = acc[tm][tn][r] + bv;
                    if constexpr (__is_same(TO, float))
                        out[n * 128 + f] = val;
                    else
                        out[n * 128 + f] = f2bf(val);
                }
            }
        }
    }
}

extern "C" void kernel_launch(void* const* d_in, const int* in_sizes, int n_in,
                              void* d_out, int out_size, void* d_ws, size_t ws_size,
                              hipStream_t stream) {
    const float* x   = (const float*)d_in[0];
    const int*   ei  = (const int*)d_in[1];
    const int*   org = (const int*)d_in[2];
    const float* Wl1 = (const float*)d_in[3];
    const float* bl1 = (const float*)d_in[4];
    const float* Wr1 = (const float*)d_in[5];
    const float* Wl2 = (const float*)d_in[6];
    const float* bl2 = (const float*)d_in[7];
    const float* Wr2 = (const float*)d_in[8];
    float* out = (float*)d_out;

    const int N = in_sizes[0] / DD;
    const int E = in_sizes[1] / 2;

    size_t szFeat = (size_t)N * DD * 2;          // bf16 feature matrix
    size_t szBase = 2 * szFeat                    // mean + h
                  + 2 * 65536                     // Wt1 + Wt2
                  + (size_t)N * 4 + 4096          // cur + bcnt + bcur
                  + (size_t)(N + 1) * 4           // off
                  + 4096                          // boff
                  + (size_t)E * 4;                // csr
    bool big = ws_size >= szBase + szFeat + 4096; // room for bf16 x too?

    char* ws = (char*)d_ws;
    unsigned short* mean = (unsigned short*)ws;  ws += szFeat;
    unsigned short* h    = (unsigned short*)ws;  ws += szFeat;
    unsigned short* xb   = nullptr;
    if (big) { xb = (unsigned short*)ws; ws += szFeat; }
    unsigned short* Wt1 = (unsigned short*)ws;  ws += 65536;
    unsigned short* Wt2 = (unsigned short*)ws;  ws += 65536;
    int* cur  = (int*)ws;  ws += (size_t)N * 4;   // fallback only
    int* bcnt = (int*)ws;  ws += 2048;            // cur+bcnt+bcur: one memset
    int* bcur = (int*)ws;  ws += 2048;
    int* off  = (int*)ws;  ws += (size_t)(N + 1) * 4;
    int* boff = (int*)ws;  ws += 4096;
    int* csr  = (int*)ws;

    // pairs buffer (E x 8 B) aliases mean+h (2*szFeat >= E*8 for this shape);
    // mean/h are first written by aggregate/gemm, strictly after build_csr
    // in stream order, so the aliasing is dead by then.
    unsigned long long* pairs = (unsigned long long*)mean;

    int nbuk = (N + 255) >> 8;                  // 391 for N=100000 (<= NBUKMAX)
    int edgeGrid = (E + 256 * PCH - 1) / (256 * PCH);

    // --- CSR build (no per-edge global atomics anywhere) ---
    hipMemsetAsync(cur, 0, (size_t)N * 4 + 4096, stream);   // cur + bcnt + bcur
    hist_buckets<<<edgeGrid, 256, 0, stream>>>(ei, E, bcnt, nbuk);
    scan_buckets<<<1, 512, 0, stream>>>(bcnt, nbuk, boff, off + N, E);
    partition_edges<<<edgeGrid, 256, 0, stream>>>(ei, E, boff, bcur, pairs, nbuk);
    build_csr<<<nbuk, 256, 0, stream>>>(pairs, boff, off, csr, cur, N);

    // --- weight prep (fragment-ordered layout; see prep_weights) ---
    prep_weights<<<64, 256, 0, stream>>>(Wl1, Wr1, Wl2, Wr2, Wt1, Wt2);

    int aggGrid  = (N + 3) / 4;
    int gemmGrid = (N + 63) / 64;

    if (big) {
        cast_bf16<<<(N * DD / 4 + 255) / 256, 256, 0, stream>>>(x, xb, N * DD / 4);
        aggregate_bf<<<aggGrid, 256, 0, stream>>>(xb, off, csr, mean, N, nullptr);
        gemm_mfma<unsigned short, unsigned short><<<gemmGrid, 256, 0, stream>>>(
            mean, xb, Wt1, bl1, h, N, N, nullptr);
    } else {
        aggregate_f32<<<aggGrid, 256, 0, stream>>>(x, off, csr, mean, N);
        gemm_mfma<float, unsigned short><<<gemmGrid, 256, 0, stream>>>(
            mean, x, Wt1, bl1, h, N, N, nullptr);
    }
    aggregate_bf<<<aggGrid, 256, 0, stream>>>(h, off, csr, mean, N, org);
    gemm_mfma<unsigned short, float><<<gemmGrid, 256, 0, stream>>>(
        mean, h, Wt2, bl2, out, N, N, org);
}